// Round 2
// baseline (4761.537 us; speedup 1.0000x reference)
//
#include <hip/hip_runtime.h>
#include <math.h>

#define EMB 50
#define HID 50
#define G4  200   // 4*HID
#define NTAG 5
#define NEGV (-10000.0f)
#define TAG_START 3
#define TAG_STOP  4
#define T_MAX 4096
#define VCHUNK 2048   // viterbi feats staging chunk (40KB LDS)

// ---------------------------------------------------------------------------
// K1: x = embed[sentence[t]];  pre_f[t][j] = b_f[j] + Wih_f[j]·x ; same for b
// pre layout: [0 .. T*200) fwd, [T*200 .. 2T*200) bwd
// ---------------------------------------------------------------------------
__global__ void k_embed_proj(const int* __restrict__ sent,
                             const float* __restrict__ embed,
                             const float* __restrict__ Wf, const float* __restrict__ bf,
                             const float* __restrict__ Wb, const float* __restrict__ bb,
                             float* __restrict__ pre, int T) {
  int t = blockIdx.x;
  int j = threadIdx.x;
  int idx = sent[t];
  const float* x = embed + (long long)idx * EMB;
  if (j < G4) {
    const float* wf = Wf + j * EMB;
    const float* wb = Wb + j * EMB;
    float af = bf[j], ab = bb[j];
#pragma unroll
    for (int k = 0; k < EMB; ++k) {
      float xk = x[k];
      af += wf[k] * xk;
      ab += wb[k] * xk;
    }
    pre[(long long)t * G4 + j] = af;
    pre[(long long)(T + t) * G4 + j] = ab;
  }
}

// ---------------------------------------------------------------------------
// K2: single-wave sequential LSTM. block 0 = fwd, block 1 = bwd. 64 threads.
// Lane j (0..49) owns hidden unit j: all 4 gate rows of Whh in registers
// (4*52 = 208 VGPRs, static-indexed). h broadcast via LDS float4 reads
// (same-address across lanes = free broadcast). NO barriers in the loop:
// single wave => in-order lgkmcnt handles the h_lds write->read dependence,
// and the depth-2 register prefetch of `pre` is never drained by a barrier.
// hs layout: [T][100]  (fwd cols 0..49, bwd cols 50..99)
// ---------------------------------------------------------------------------
__global__ __launch_bounds__(64, 1) void k_lstm(const float* __restrict__ pre,
                       const float* __restrict__ Whh_f,
                       const float* __restrict__ Whh_b,
                       const float* __restrict__ h0, const float* __restrict__ c0,
                       float* __restrict__ hs, int T) {
  const int d = blockIdx.x;
  const int j = threadIdx.x;            // 0..63
  const int jr = (j < HID) ? j : 0;     // lanes 50..63 mirror lane 0 (results unused)
  const float* __restrict__ Whh  = d ? Whh_b : Whh_f;
  const float* __restrict__ preD = pre + (long long)d * T * G4;

  __shared__ __align__(16) float h_lds[52];

  float wi[52], wf[52], wg[52], wo[52];
#pragma unroll
  for (int k = 0; k < HID; ++k) {
    wi[k] = Whh[(jr      ) * HID + k];
    wf[k] = Whh[(jr +  50) * HID + k];
    wg[k] = Whh[(jr + 100) * HID + k];
    wo[k] = Whh[(jr + 150) * HID + k];
  }
  wi[50] = 0.f; wi[51] = 0.f; wf[50] = 0.f; wf[51] = 0.f;
  wg[50] = 0.f; wg[51] = 0.f; wo[50] = 0.f; wo[51] = 0.f;

  float c = (j < HID) ? c0[d * HID + j] : 0.f;
  if (j < HID) h_lds[j] = h0[d * HID + j];
  if (j >= HID && j < 52) h_lds[j] = 0.f;
  __syncthreads();   // once, before the loop

  const int s = d ? -1 : 1;
  int t = d ? (T - 1) : 0;

  // depth-2 register prefetch of pre rows
  const float* p = preD + (long long)t * G4;
  float c_i = p[jr], c_f = p[jr + 50], c_g = p[jr + 100], c_o = p[jr + 150];
  int t1 = t + s; if (t1 < 0) t1 = 0; if (t1 > T - 1) t1 = T - 1;
  p = preD + (long long)t1 * G4;
  float n_i = p[jr], n_f = p[jr + 50], n_g = p[jr + 100], n_o = p[jr + 150];

  for (int it = 0; it < T; ++it) {
    int t2 = t + 2 * s; if (t2 < 0) t2 = 0; if (t2 > T - 1) t2 = T - 1;
    p = preD + (long long)t2 * G4;
    float m_i = p[jr], m_f = p[jr + 50], m_g = p[jr + 100], m_o = p[jr + 150];

    // z = pre + Whh·h  — same accumulator grouping as the validated round-1 code
    float ai0 = 0.f, ai1 = 0.f, ai2 = 0.f, ai3 = 0.f;
    float af0 = 0.f, af1 = 0.f, af2 = 0.f, af3 = 0.f;
    float ag0 = 0.f, ag1 = 0.f, ag2 = 0.f, ag3 = 0.f;
    float ao0 = 0.f, ao1 = 0.f, ao2 = 0.f, ao3 = 0.f;
#pragma unroll
    for (int k4 = 0; k4 < 13; ++k4) {
      const float4 h4 = *(const float4*)&h_lds[4 * k4];
      ai0 += wi[4 * k4 + 0] * h4.x; ai1 += wi[4 * k4 + 1] * h4.y;
      ai2 += wi[4 * k4 + 2] * h4.z; ai3 += wi[4 * k4 + 3] * h4.w;
      af0 += wf[4 * k4 + 0] * h4.x; af1 += wf[4 * k4 + 1] * h4.y;
      af2 += wf[4 * k4 + 2] * h4.z; af3 += wf[4 * k4 + 3] * h4.w;
      ag0 += wg[4 * k4 + 0] * h4.x; ag1 += wg[4 * k4 + 1] * h4.y;
      ag2 += wg[4 * k4 + 2] * h4.z; ag3 += wg[4 * k4 + 3] * h4.w;
      ao0 += wo[4 * k4 + 0] * h4.x; ao1 += wo[4 * k4 + 1] * h4.y;
      ao2 += wo[4 * k4 + 2] * h4.z; ao3 += wo[4 * k4 + 3] * h4.w;
    }
    float zi = c_i + ((ai0 + ai1) + (ai2 + ai3));
    float zf = c_f + ((af0 + af1) + (af2 + af3));
    float zg = c_g + ((ag0 + ag1) + (ag2 + ag3));
    float zo = c_o + ((ao0 + ao1) + (ao2 + ao3));

    // activations — identical formulas to round-1 (e = exp(-z) shared form)
    float ei = __expf(-zi); float si = 1.f / (1.f + ei);
    float ef = __expf(-zf); float sf = 1.f / (1.f + ef);
    float eg = __expf(-zg); float tg = 2.f / (1.f + eg * eg) - 1.f;
    float eo = __expf(-zo); float so = 1.f / (1.f + eo);
    c = sf * c + si * tg;
    float e2 = __expf(-2.f * c);
    float tc = 2.f / (1.f + e2) - 1.f;
    float h = so * tc;

    if (j < HID) {
      h_lds[j] = h;                                     // broadcast for next step
      hs[(long long)t * (2 * HID) + d * HID + j] = h;   // fire-and-forget
    }

    c_i = n_i; c_f = n_f; c_g = n_g; c_o = n_o;
    n_i = m_i; n_f = m_f; n_g = m_g; n_o = m_o;
    t += s;
  }
}

// ---------------------------------------------------------------------------
// K3: feats[t][m] = bt[m] + Wt[m]·hs[t]   (dot over 100)
// ---------------------------------------------------------------------------
__global__ void k_feats(const float* __restrict__ hs, const float* __restrict__ Wt,
                        const float* __restrict__ bt, float* __restrict__ feats, int T) {
  int g = blockIdx.x * blockDim.x + threadIdx.x;
  if (g >= T * NTAG) return;
  int t = g / NTAG, m = g % NTAG;
  const float* h = hs + (long long)t * (2 * HID);
  const float* w = Wt + m * (2 * HID);
  float a = bt[m];
#pragma unroll
  for (int k = 0; k < 2 * HID; ++k) a += w[k] * h[k];
  feats[g] = a;
}

// ---------------------------------------------------------------------------
// K4a: serial Viterbi forward scan, 1 block x 64 threads (single wave).
// feats staged into LDS in two 40KB halves (cooperative float4 loads), so the
// serial chain reads LDS (~64cy, hoisted by unroll) instead of L2/L3 (~400cy).
// All lanes compute redundantly; lane 0 stores fvh/terminal.
// ---------------------------------------------------------------------------
__global__ __launch_bounds__(64, 1) void k_vscan(const float* __restrict__ feats,
                        const float* __restrict__ trans,
                        float* __restrict__ fvh, float* __restrict__ misc,
                        float* __restrict__ out, int T) {
  __shared__ float sfeat[VCHUNK * NTAG];   // 40 KB
  const int tid = threadIdx.x;

  float tr[NTAG * NTAG];
#pragma unroll
  for (int i = 0; i < NTAG * NTAG; ++i) tr[i] = trans[i];

  float f0 = NEGV, f1 = NEGV, f2 = NEGV, f3 = 0.f, f4 = NEGV;

  for (int base = 0; base < T; base += VCHUNK) {
    // stage this half: VCHUNK*5 floats = 2560 float4 (16B-aligned: base*5*4 % 16 == 0)
    const float4* src = (const float4*)(feats + (long long)base * NTAG);
    float4* dst = (float4*)sfeat;
    for (int i = tid; i < VCHUNK * NTAG / 4; i += 64) dst[i] = src[i];
    __syncthreads();

#pragma unroll 4
    for (int u = 0; u < VCHUNK; ++u) {
      int t = base + u;
      if (tid == 0) {
        fvh[t * 5 + 0] = f0; fvh[t * 5 + 1] = f1; fvh[t * 5 + 2] = f2;
        fvh[t * 5 + 3] = f3; fvh[t * 5 + 4] = f4;
      }
      float ft0 = sfeat[u * 5 + 0], ft1 = sfeat[u * 5 + 1], ft2 = sfeat[u * 5 + 2];
      float ft3 = sfeat[u * 5 + 3], ft4 = sfeat[u * 5 + 4];
      float n0 = fmaxf(fmaxf(fmaxf(f0 + tr[0],  f1 + tr[1]),  fmaxf(f2 + tr[2],  f3 + tr[3])),  f4 + tr[4])  + ft0;
      float n1 = fmaxf(fmaxf(fmaxf(f0 + tr[5],  f1 + tr[6]),  fmaxf(f2 + tr[7],  f3 + tr[8])),  f4 + tr[9])  + ft1;
      float n2 = fmaxf(fmaxf(fmaxf(f0 + tr[10], f1 + tr[11]), fmaxf(f2 + tr[12], f3 + tr[13])), f4 + tr[14]) + ft2;
      float n3 = fmaxf(fmaxf(fmaxf(f0 + tr[15], f1 + tr[16]), fmaxf(f2 + tr[17], f3 + tr[18])), f4 + tr[19]) + ft3;
      float n4 = fmaxf(fmaxf(fmaxf(f0 + tr[20], f1 + tr[21]), fmaxf(f2 + tr[22], f3 + tr[23])), f4 + tr[24]) + ft4;
      f0 = n0; f1 = n1; f2 = n2; f3 = n3; f4 = n4;
    }
    __syncthreads();
  }

  // terminal = fv + trans[STOP][:]; first-max argmax (same order as reference)
  float b0 = f0 + tr[TAG_STOP * 5 + 0], b1 = f1 + tr[TAG_STOP * 5 + 1];
  float b2 = f2 + tr[TAG_STOP * 5 + 2], b3 = f3 + tr[TAG_STOP * 5 + 3];
  float b4 = f4 + tr[TAG_STOP * 5 + 4];
  int last = 0; float best = b0;
  if (b1 > best) { best = b1; last = 1; }
  if (b2 > best) { best = b2; last = 2; }
  if (b3 > best) { best = b3; last = 3; }
  if (b4 > best) { best = b4; last = 4; }
  if (tid == 0) { out[T] = best; misc[0] = (float)last; }
}

// ---------------------------------------------------------------------------
// K4b: parallel backpointer recompute + suffix-composition backtrace.
// ---------------------------------------------------------------------------
__global__ __launch_bounds__(1024) void k_vbt(const float* __restrict__ trans,
                        const float* __restrict__ fvh, const float* __restrict__ misc,
                        float* __restrict__ out, int T) {
  __shared__ unsigned int bufA[T_MAX];
  __shared__ unsigned int bufB[T_MAX];
  int tid = threadIdx.x;

  // phase 2: bufA[t] = pack(bp_{t+1}) for t<T-1 ; bufA[T-1] = identity
  {
    float tr[NTAG * NTAG];
#pragma unroll
    for (int i = 0; i < NTAG * NTAG; ++i) tr[i] = trans[i];
    for (int t = tid; t < T; t += 1024) {
      unsigned pack;
      if (t == T - 1) {
        pack = 0u | (1u << 3) | (2u << 6) | (3u << 9) | (4u << 12);
      } else {
        const float* fv = fvh + (long long)(t + 1) * 5;
        float g0 = fv[0], g1 = fv[1], g2 = fv[2], g3 = fv[3], g4 = fv[4];
        pack = 0u;
#pragma unroll
        for (int nx = 0; nx < NTAG; ++nx) {
          float v0 = g0 + tr[nx * 5 + 0], v1 = g1 + tr[nx * 5 + 1], v2 = g2 + tr[nx * 5 + 2];
          float v3 = g3 + tr[nx * 5 + 3], v4 = g4 + tr[nx * 5 + 4];
          int bi = 0; float bv = v0;
          if (v1 > bv) { bv = v1; bi = 1; }
          if (v2 > bv) { bv = v2; bi = 2; }
          if (v3 > bv) { bv = v3; bi = 3; }
          if (v4 > bv) { bv = v4; bi = 4; }
          pack |= (unsigned)bi << (3 * nx);
        }
      }
      bufA[t] = pack;
    }
  }
  __syncthreads();

  // phase 3: suffix composition scan: A[t] <- A[t] ∘ A[t+d]
  unsigned int* cur = bufA;
  unsigned int* nxt = bufB;
  for (int dstep = 1; dstep < T; dstep <<= 1) {
    for (int t = tid; t < T; t += 1024) {
      unsigned v = cur[t];
      int u = t + dstep;
      if (u < T) {
        unsigned q = cur[u];
        unsigned r = 0u;
#pragma unroll
        for (int x = 0; x < NTAG; ++x) {
          unsigned qq = (q >> (3 * x)) & 7u;
          unsigned pp = (v >> (3 * qq)) & 7u;
          r |= pp << (3 * x);
        }
        v = r;
      }
      nxt[t] = v;
    }
    __syncthreads();
    unsigned int* tmp = cur; cur = nxt; nxt = tmp;
  }

  int last = (int)misc[0];
  for (int t = tid; t < T; t += 1024) {
    out[t] = (float)((cur[t] >> (3 * last)) & 7u);
  }
}

// ---------------------------------------------------------------------------
extern "C" void kernel_launch(void* const* d_in, const int* in_sizes, int n_in,
                              void* d_out, int out_size, void* d_ws, size_t ws_size,
                              hipStream_t stream) {
  const int*   sent  = (const int*)  d_in[0];
  const float* embed = (const float*)d_in[1];
  const float* Wih_f = (const float*)d_in[2];
  const float* Whh_f = (const float*)d_in[3];
  const float* b_f   = (const float*)d_in[4];
  const float* Wih_b = (const float*)d_in[5];
  const float* Whh_b = (const float*)d_in[6];
  const float* b_b   = (const float*)d_in[7];
  const float* Wt    = (const float*)d_in[8];
  const float* bt    = (const float*)d_in[9];
  const float* trans = (const float*)d_in[10];
  const float* h0    = (const float*)d_in[11];
  const float* c0    = (const float*)d_in[12];
  int T = in_sizes[0];

  float* out = (float*)d_out;
  float* pre   = (float*)d_ws;                       // 2*T*200 floats
  float* hs    = pre + 2 * (size_t)T * G4;           // T*100
  float* feats = hs + (size_t)T * 2 * HID;           // T*5
  float* fvh   = feats + (size_t)T * NTAG;           // (T+1)*5
  float* misc  = fvh + (size_t)(T + 1) * NTAG;       // 16

  k_embed_proj<<<T, 256, 0, stream>>>(sent, embed, Wih_f, b_f, Wih_b, b_b, pre, T);
  k_lstm<<<2, 64, 0, stream>>>(pre, Whh_f, Whh_b, h0, c0, hs, T);
  k_feats<<<(T * NTAG + 255) / 256, 256, 0, stream>>>(hs, Wt, bt, feats, T);
  k_vscan<<<1, 64, 0, stream>>>(feats, trans, fvh, misc, out, T);
  k_vbt<<<1, 1024, 0, stream>>>(trans, fvh, misc, out, T);
}

// Round 3
// 4544.128 us; speedup vs baseline: 1.0478x; 1.0478x over previous
//
#include <hip/hip_runtime.h>
#include <math.h>

#define EMB 50
#define HID 50
#define G4  200   // 4*HID
#define NTAG 5
#define NEGV (-10000.0f)
#define TAG_START 3
#define TAG_STOP  4
#define T_MAX 4096
#define VCHUNK 2048   // viterbi feats staging chunk (40KB LDS)

// ---------------------------------------------------------------------------
// K1: x = embed[sentence[t]];  pre_f[t][j] = b_f[j] + Wih_f[j]·x ; same for b
// pre layout: [0 .. T*200) fwd, [T*200 .. 2T*200) bwd
// ---------------------------------------------------------------------------
__global__ void k_embed_proj(const int* __restrict__ sent,
                             const float* __restrict__ embed,
                             const float* __restrict__ Wf, const float* __restrict__ bf,
                             const float* __restrict__ Wb, const float* __restrict__ bb,
                             float* __restrict__ pre, int T) {
  int t = blockIdx.x;
  int j = threadIdx.x;
  int idx = sent[t];
  const float* x = embed + (long long)idx * EMB;
  if (j < G4) {
    const float* wf = Wf + j * EMB;
    const float* wb = Wb + j * EMB;
    float af = bf[j], ab = bb[j];
#pragma unroll
    for (int k = 0; k < EMB; ++k) {
      float xk = x[k];
      af += wf[k] * xk;
      ab += wb[k] * xk;
    }
    pre[(long long)t * G4 + j] = af;
    pre[(long long)(T + t) * G4 + j] = ab;
  }
}

// ---------------------------------------------------------------------------
// K2: single-wave sequential LSTM. block 0 = fwd, block 1 = bwd. 64 threads.
// Lane j (0..49) owns hidden unit j: all 4 gate rows of Whh in registers
// (200 VGPRs, static-indexed). amdgpu_waves_per_eu(1,1) lifts the VGPR cap
// to the full file so the weights actually STAY in registers (round-2 bug:
// occupancy heuristic capped VGPR=160 -> 3.2GB of scratch-spill traffic).
// h broadcast via LDS reads (same-address across lanes = free broadcast).
// NO barriers in the loop: single wave => in-order lgkmcnt handles the
// h_lds write->read dependence; depth-2 register prefetch of `pre` covers
// L2/L3 latency. hs layout: [T][100] (fwd cols 0..49, bwd cols 50..99)
// ---------------------------------------------------------------------------
__global__
__attribute__((amdgpu_flat_work_group_size(64, 64), amdgpu_waves_per_eu(1, 1)))
void k_lstm(const float* __restrict__ pre,
            const float* __restrict__ Whh_f,
            const float* __restrict__ Whh_b,
            const float* __restrict__ h0, const float* __restrict__ c0,
            float* __restrict__ hs, int T) {
  const int d = blockIdx.x;
  const int j = threadIdx.x;            // 0..63
  const int jr = (j < HID) ? j : 0;     // lanes 50..63 mirror lane 0 (results unused)
  const float* __restrict__ Whh  = d ? Whh_b : Whh_f;
  const float* __restrict__ preD = pre + (long long)d * T * G4;

  __shared__ __align__(16) float h_lds[52];

  float wi[50], wf[50], wg[50], wo[50];
#pragma unroll
  for (int k = 0; k < HID; ++k) {
    wi[k] = Whh[(jr      ) * HID + k];
    wf[k] = Whh[(jr +  50) * HID + k];
    wg[k] = Whh[(jr + 100) * HID + k];
    wo[k] = Whh[(jr + 150) * HID + k];
  }

  float c = (j < HID) ? c0[d * HID + j] : 0.f;
  if (j < HID) h_lds[j] = h0[d * HID + j];
  if (j >= HID && j < 52) h_lds[j] = 0.f;
  __syncthreads();   // once, before the loop

  const int s = d ? -1 : 1;
  int t = d ? (T - 1) : 0;

  // depth-2 register prefetch of pre rows
  const float* p = preD + (long long)t * G4;
  float c_i = p[jr], c_f = p[jr + 50], c_g = p[jr + 100], c_o = p[jr + 150];
  int t1 = t + s; if (t1 < 0) t1 = 0; if (t1 > T - 1) t1 = T - 1;
  p = preD + (long long)t1 * G4;
  float n_i = p[jr], n_f = p[jr + 50], n_g = p[jr + 100], n_o = p[jr + 150];

  for (int it = 0; it < T; ++it) {
    int t2 = t + 2 * s; if (t2 < 0) t2 = 0; if (t2 > T - 1) t2 = T - 1;
    p = preD + (long long)t2 * G4;
    float m_i = p[jr], m_f = p[jr + 50], m_g = p[jr + 100], m_o = p[jr + 150];

    // z = pre + Whh·h  — same accumulator grouping as the validated round-2 code
    // (k4 = 0..11 as float4; tail k = 48,49 -> contributes to acc0/acc1 only,
    //  exactly matching the old padded k4=12 step where w[50]=w[51]=0)
    float ai0 = 0.f, ai1 = 0.f, ai2 = 0.f, ai3 = 0.f;
    float af0 = 0.f, af1 = 0.f, af2 = 0.f, af3 = 0.f;
    float ag0 = 0.f, ag1 = 0.f, ag2 = 0.f, ag3 = 0.f;
    float ao0 = 0.f, ao1 = 0.f, ao2 = 0.f, ao3 = 0.f;
#pragma unroll
    for (int k4 = 0; k4 < 12; ++k4) {
      const float4 h4 = *(const float4*)&h_lds[4 * k4];
      ai0 += wi[4 * k4 + 0] * h4.x; ai1 += wi[4 * k4 + 1] * h4.y;
      ai2 += wi[4 * k4 + 2] * h4.z; ai3 += wi[4 * k4 + 3] * h4.w;
      af0 += wf[4 * k4 + 0] * h4.x; af1 += wf[4 * k4 + 1] * h4.y;
      af2 += wf[4 * k4 + 2] * h4.z; af3 += wf[4 * k4 + 3] * h4.w;
      ag0 += wg[4 * k4 + 0] * h4.x; ag1 += wg[4 * k4 + 1] * h4.y;
      ag2 += wg[4 * k4 + 2] * h4.z; ag3 += wg[4 * k4 + 3] * h4.w;
      ao0 += wo[4 * k4 + 0] * h4.x; ao1 += wo[4 * k4 + 1] * h4.y;
      ao2 += wo[4 * k4 + 2] * h4.z; ao3 += wo[4 * k4 + 3] * h4.w;
    }
    {
      const float2 h2 = *(const float2*)&h_lds[48];
      ai0 += wi[48] * h2.x; ai1 += wi[49] * h2.y;
      af0 += wf[48] * h2.x; af1 += wf[49] * h2.y;
      ag0 += wg[48] * h2.x; ag1 += wg[49] * h2.y;
      ao0 += wo[48] * h2.x; ao1 += wo[49] * h2.y;
    }
    float zi = c_i + ((ai0 + ai1) + (ai2 + ai3));
    float zf = c_f + ((af0 + af1) + (af2 + af3));
    float zg = c_g + ((ag0 + ag1) + (ag2 + ag3));
    float zo = c_o + ((ao0 + ao1) + (ao2 + ao3));

    // activations — identical formulas to round-2 (e = exp(-z) shared form)
    float ei = __expf(-zi); float si = 1.f / (1.f + ei);
    float ef = __expf(-zf); float sf = 1.f / (1.f + ef);
    float eg = __expf(-zg); float tg = 2.f / (1.f + eg * eg) - 1.f;
    float eo = __expf(-zo); float so = 1.f / (1.f + eo);
    c = sf * c + si * tg;
    float e2 = __expf(-2.f * c);
    float tc = 2.f / (1.f + e2) - 1.f;
    float h = so * tc;

    if (j < HID) {
      h_lds[j] = h;                                     // broadcast for next step
      hs[(long long)t * (2 * HID) + d * HID + j] = h;   // fire-and-forget
    }

    c_i = n_i; c_f = n_f; c_g = n_g; c_o = n_o;
    n_i = m_i; n_f = m_f; n_g = m_g; n_o = m_o;
    t += s;
  }
}

// ---------------------------------------------------------------------------
// K3: feats[t][m] = bt[m] + Wt[m]·hs[t]   (dot over 100)
// ---------------------------------------------------------------------------
__global__ void k_feats(const float* __restrict__ hs, const float* __restrict__ Wt,
                        const float* __restrict__ bt, float* __restrict__ feats, int T) {
  int g = blockIdx.x * blockDim.x + threadIdx.x;
  if (g >= T * NTAG) return;
  int t = g / NTAG, m = g % NTAG;
  const float* h = hs + (long long)t * (2 * HID);
  const float* w = Wt + m * (2 * HID);
  float a = bt[m];
#pragma unroll
  for (int k = 0; k < 2 * HID; ++k) a += w[k] * h[k];
  feats[g] = a;
}

// ---------------------------------------------------------------------------
// K4a: serial Viterbi forward scan, 1 block x 64 threads (single wave).
// feats staged into LDS in two 40KB halves (cooperative float4 loads), so the
// serial chain reads LDS instead of L2/L3. Lane 0 stores fvh/terminal.
// ---------------------------------------------------------------------------
__global__ __launch_bounds__(64, 1) void k_vscan(const float* __restrict__ feats,
                        const float* __restrict__ trans,
                        float* __restrict__ fvh, float* __restrict__ misc,
                        float* __restrict__ out, int T) {
  __shared__ float sfeat[VCHUNK * NTAG];   // 40 KB
  const int tid = threadIdx.x;

  float tr[NTAG * NTAG];
#pragma unroll
  for (int i = 0; i < NTAG * NTAG; ++i) tr[i] = trans[i];

  float f0 = NEGV, f1 = NEGV, f2 = NEGV, f3 = 0.f, f4 = NEGV;

  for (int base = 0; base < T; base += VCHUNK) {
    const float4* src = (const float4*)(feats + (long long)base * NTAG);
    float4* dst = (float4*)sfeat;
    for (int i = tid; i < VCHUNK * NTAG / 4; i += 64) dst[i] = src[i];
    __syncthreads();

#pragma unroll 4
    for (int u = 0; u < VCHUNK; ++u) {
      int t = base + u;
      if (tid == 0) {
        fvh[t * 5 + 0] = f0; fvh[t * 5 + 1] = f1; fvh[t * 5 + 2] = f2;
        fvh[t * 5 + 3] = f3; fvh[t * 5 + 4] = f4;
      }
      float ft0 = sfeat[u * 5 + 0], ft1 = sfeat[u * 5 + 1], ft2 = sfeat[u * 5 + 2];
      float ft3 = sfeat[u * 5 + 3], ft4 = sfeat[u * 5 + 4];
      float n0 = fmaxf(fmaxf(fmaxf(f0 + tr[0],  f1 + tr[1]),  fmaxf(f2 + tr[2],  f3 + tr[3])),  f4 + tr[4])  + ft0;
      float n1 = fmaxf(fmaxf(fmaxf(f0 + tr[5],  f1 + tr[6]),  fmaxf(f2 + tr[7],  f3 + tr[8])),  f4 + tr[9])  + ft1;
      float n2 = fmaxf(fmaxf(fmaxf(f0 + tr[10], f1 + tr[11]), fmaxf(f2 + tr[12], f3 + tr[13])), f4 + tr[14]) + ft2;
      float n3 = fmaxf(fmaxf(fmaxf(f0 + tr[15], f1 + tr[16]), fmaxf(f2 + tr[17], f3 + tr[18])), f4 + tr[19]) + ft3;
      float n4 = fmaxf(fmaxf(fmaxf(f0 + tr[20], f1 + tr[21]), fmaxf(f2 + tr[22], f3 + tr[23])), f4 + tr[24]) + ft4;
      f0 = n0; f1 = n1; f2 = n2; f3 = n3; f4 = n4;
    }
    __syncthreads();
  }

  float b0 = f0 + tr[TAG_STOP * 5 + 0], b1 = f1 + tr[TAG_STOP * 5 + 1];
  float b2 = f2 + tr[TAG_STOP * 5 + 2], b3 = f3 + tr[TAG_STOP * 5 + 3];
  float b4 = f4 + tr[TAG_STOP * 5 + 4];
  int last = 0; float best = b0;
  if (b1 > best) { best = b1; last = 1; }
  if (b2 > best) { best = b2; last = 2; }
  if (b3 > best) { best = b3; last = 3; }
  if (b4 > best) { best = b4; last = 4; }
  if (tid == 0) { out[T] = best; misc[0] = (float)last; }
}

// ---------------------------------------------------------------------------
// K4b: parallel backpointer recompute + suffix-composition backtrace.
// ---------------------------------------------------------------------------
__global__ __launch_bounds__(1024) void k_vbt(const float* __restrict__ trans,
                        const float* __restrict__ fvh, const float* __restrict__ misc,
                        float* __restrict__ out, int T) {
  __shared__ unsigned int bufA[T_MAX];
  __shared__ unsigned int bufB[T_MAX];
  int tid = threadIdx.x;

  {
    float tr[NTAG * NTAG];
#pragma unroll
    for (int i = 0; i < NTAG * NTAG; ++i) tr[i] = trans[i];
    for (int t = tid; t < T; t += 1024) {
      unsigned pack;
      if (t == T - 1) {
        pack = 0u | (1u << 3) | (2u << 6) | (3u << 9) | (4u << 12);
      } else {
        const float* fv = fvh + (long long)(t + 1) * 5;
        float g0 = fv[0], g1 = fv[1], g2 = fv[2], g3 = fv[3], g4 = fv[4];
        pack = 0u;
#pragma unroll
        for (int nx = 0; nx < NTAG; ++nx) {
          float v0 = g0 + tr[nx * 5 + 0], v1 = g1 + tr[nx * 5 + 1], v2 = g2 + tr[nx * 5 + 2];
          float v3 = g3 + tr[nx * 5 + 3], v4 = g4 + tr[nx * 5 + 4];
          int bi = 0; float bv = v0;
          if (v1 > bv) { bv = v1; bi = 1; }
          if (v2 > bv) { bv = v2; bi = 2; }
          if (v3 > bv) { bv = v3; bi = 3; }
          if (v4 > bv) { bv = v4; bi = 4; }
          pack |= (unsigned)bi << (3 * nx);
        }
      }
      bufA[t] = pack;
    }
  }
  __syncthreads();

  unsigned int* cur = bufA;
  unsigned int* nxt = bufB;
  for (int dstep = 1; dstep < T; dstep <<= 1) {
    for (int t = tid; t < T; t += 1024) {
      unsigned v = cur[t];
      int u = t + dstep;
      if (u < T) {
        unsigned q = cur[u];
        unsigned r = 0u;
#pragma unroll
        for (int x = 0; x < NTAG; ++x) {
          unsigned qq = (q >> (3 * x)) & 7u;
          unsigned pp = (v >> (3 * qq)) & 7u;
          r |= pp << (3 * x);
        }
        v = r;
      }
      nxt[t] = v;
    }
    __syncthreads();
    unsigned int* tmp = cur; cur = nxt; nxt = tmp;
  }

  int last = (int)misc[0];
  for (int t = tid; t < T; t += 1024) {
    out[t] = (float)((cur[t] >> (3 * last)) & 7u);
  }
}

// ---------------------------------------------------------------------------
extern "C" void kernel_launch(void* const* d_in, const int* in_sizes, int n_in,
                              void* d_out, int out_size, void* d_ws, size_t ws_size,
                              hipStream_t stream) {
  const int*   sent  = (const int*)  d_in[0];
  const float* embed = (const float*)d_in[1];
  const float* Wih_f = (const float*)d_in[2];
  const float* Whh_f = (const float*)d_in[3];
  const float* b_f   = (const float*)d_in[4];
  const float* Wih_b = (const float*)d_in[5];
  const float* Whh_b = (const float*)d_in[6];
  const float* b_b   = (const float*)d_in[7];
  const float* Wt    = (const float*)d_in[8];
  const float* bt    = (const float*)d_in[9];
  const float* trans = (const float*)d_in[10];
  const float* h0    = (const float*)d_in[11];
  const float* c0    = (const float*)d_in[12];
  int T = in_sizes[0];

  float* out = (float*)d_out;
  float* pre   = (float*)d_ws;                       // 2*T*200 floats
  float* hs    = pre + 2 * (size_t)T * G4;           // T*100
  float* feats = hs + (size_t)T * 2 * HID;           // T*5
  float* fvh   = feats + (size_t)T * NTAG;           // (T+1)*5
  float* misc  = fvh + (size_t)(T + 1) * NTAG;       // 16

  k_embed_proj<<<T, 256, 0, stream>>>(sent, embed, Wih_f, b_f, Wih_b, b_b, pre, T);
  k_lstm<<<2, 64, 0, stream>>>(pre, Whh_f, Whh_b, h0, c0, hs, T);
  k_feats<<<(T * NTAG + 255) / 256, 256, 0, stream>>>(hs, Wt, bt, feats, T);
  k_vscan<<<1, 64, 0, stream>>>(feats, trans, fvh, misc, out, T);
  k_vbt<<<1, 1024, 0, stream>>>(trans, fvh, misc, out, T);
}

// Round 5
// 2696.286 us; speedup vs baseline: 1.7660x; 1.6853x over previous
//
#include <hip/hip_runtime.h>
#include <math.h>

#define EMB 50
#define HID 50
#define G4  200   // 4*HID
#define NTAG 5
#define NEGV (-10000.0f)
#define TAG_START 3
#define TAG_STOP  4
#define T_MAX 4096
#define VCHUNK 2048   // viterbi feats staging chunk (40KB LDS)

// ---------------------------------------------------------------------------
// K1: x = embed[sentence[t]];  pre_f[t][j] = b_f[j] + Wih_f[j]·x ; same for b
// pre layout: [0 .. T*200) fwd, [T*200 .. 2T*200) bwd
// ---------------------------------------------------------------------------
__global__ void k_embed_proj(const int* __restrict__ sent,
                             const float* __restrict__ embed,
                             const float* __restrict__ Wf, const float* __restrict__ bf,
                             const float* __restrict__ Wb, const float* __restrict__ bb,
                             float* __restrict__ pre, int T) {
  int t = blockIdx.x;
  int j = threadIdx.x;
  int idx = sent[t];
  const float* x = embed + (long long)idx * EMB;
  if (j < G4) {
    const float* wf = Wf + j * EMB;
    const float* wb = Wb + j * EMB;
    float af = bf[j], ab = bb[j];
#pragma unroll
    for (int k = 0; k < EMB; ++k) {
      float xk = x[k];
      af += wf[k] * xk;
      ab += wb[k] * xk;
    }
    pre[(long long)t * G4 + j] = af;
    pre[(long long)(T + t) * G4 + j] = ab;
  }
}

// ---------------------------------------------------------------------------
// K2: sequential LSTM, quad-per-unit layout. block 0 = fwd, block 1 = bwd.
// 256 threads: tid -> (unit j = tid>>2, gate g = tid&3). Gate rows of Whh:
// row = g*50 + j. The 4 gates of unit j are ADJACENT LANES of one wave, so
// the i/f/g/o combine is 3 __shfl_xor + selects — no LDS, no extra barrier.
// Weights live in NAMED float4 registers (w0..w12) — SROA-proof, cannot
// spill to scratch (rounds 1-3 bug: weight arrays stayed in scratch ->
// 3.2GB/launch HBM traffic -> latency-bound at ~2300cy/step).
// h double-buffered in LDS (hA/hB, statically unrolled x2); ONE barrier per
// step via inline asm "s_waitcnt lgkmcnt(0); s_barrier" — no vmcnt drain, so
// the depth-2 pre-prefetch and hs stores stay in flight across the barrier.
// ---------------------------------------------------------------------------
#define LDX(K, OFF) float4 x##K = *(const float4*)&HR[OFF];
#define FMA4(K) a0 += w##K.x * x##K.x; a1 += w##K.y * x##K.y; \
                a2 += w##K.z * x##K.z; a3 += w##K.w * x##K.w;

#define LSTM_STEP(HRbuf, HWbuf)                                              \
  {                                                                          \
    const float* HR = HRbuf;                                                 \
    float*       HW = HWbuf;                                                 \
    int t2 = t + 2 * s; t2 = t2 < 0 ? 0 : (t2 > T - 1 ? T - 1 : t2);         \
    float m_pre = preD[(long long)t2 * G4 + col];                            \
    LDX(0, 0)  LDX(1, 4)  LDX(2, 8)  LDX(3, 12) LDX(4, 16)  LDX(5, 20)      \
    LDX(6, 24) LDX(7, 28) LDX(8, 32) LDX(9, 36) LDX(10, 40) LDX(11, 44)     \
    float2 x12 = *(const float2*)&HR[48];                                    \
    float a0 = 0.f, a1 = 0.f, a2 = 0.f, a3 = 0.f;                            \
    FMA4(0) FMA4(1) FMA4(2) FMA4(3) FMA4(4)  FMA4(5)                         \
    FMA4(6) FMA4(7) FMA4(8) FMA4(9) FMA4(10) FMA4(11)                        \
    a0 += w12.x * x12.x; a1 += w12.y * x12.y;                                \
    float z = c_pre + ((a0 + a1) + (a2 + a3));                               \
    float e = __expf(-z);                                                    \
    float sig = 1.f / (1.f + e);                                             \
    float th  = 2.f / (1.f + e * e) - 1.f;                                   \
    float a = (gate == 2) ? th : sig;                                        \
    float s1v = __shfl_xor(a, 1);                                            \
    float s2v = __shfl_xor(a, 2);                                            \
    float s3v = __shfl_xor(a, 3);                                            \
    float iv = (gate == 0) ? a   : (gate == 1) ? s1v : (gate == 2) ? s2v : s3v; \
    float fv = (gate == 0) ? s1v : (gate == 1) ? a   : (gate == 2) ? s3v : s2v; \
    float gv = (gate == 0) ? s2v : (gate == 1) ? s3v : (gate == 2) ? a   : s1v; \
    float ov = (gate == 0) ? s3v : (gate == 1) ? s2v : (gate == 2) ? s1v : a;   \
    c = fv * c + iv * gv;                                                    \
    float e2 = __expf(-2.f * c);                                             \
    float tc = 2.f / (1.f + e2) - 1.f;                                       \
    float h = ov * tc;                                                       \
    if (wr) {                                                                \
      HW[jq] = h;                                                            \
      hs[(long long)t * (2 * HID) + d * HID + jq] = h;                       \
    }                                                                        \
    asm volatile("s_waitcnt lgkmcnt(0)\n\ts_barrier" ::: "memory");          \
    c_pre = n_pre; n_pre = m_pre;                                            \
    t += s;                                                                  \
  }

__global__ __launch_bounds__(256, 1)
void k_lstm(const float* __restrict__ pre,
            const float* __restrict__ Whh_f,
            const float* __restrict__ Whh_b,
            const float* __restrict__ h0, const float* __restrict__ c0,
            float* __restrict__ hs, int T) {
  const int d    = blockIdx.x;
  const int tid  = threadIdx.x;           // 0..255
  const int j    = tid >> 2;              // unit 0..63 (valid < 50)
  const int gate = tid & 3;               // 0=i 1=f 2=g 3=o
  const int jq   = (j < HID) ? j : 0;     // clamp for idle quads
  const bool wr  = (gate == 0) && (j < HID);
  const int col  = gate * HID + jq;       // column in pre row
  const float* __restrict__ Whh  = d ? Whh_b : Whh_f;
  const float* __restrict__ preD = pre + (long long)d * T * G4;

  __shared__ __align__(16) float hA[52];
  __shared__ __align__(16) float hB[52];

  // weights: row (gate*50 + jq) of Whh, as named registers (SROA-proof)
  const float* wrow = Whh + (long long)(gate * HID + jq) * HID;
  float4 w0  = make_float4(wrow[0],  wrow[1],  wrow[2],  wrow[3]);
  float4 w1  = make_float4(wrow[4],  wrow[5],  wrow[6],  wrow[7]);
  float4 w2  = make_float4(wrow[8],  wrow[9],  wrow[10], wrow[11]);
  float4 w3  = make_float4(wrow[12], wrow[13], wrow[14], wrow[15]);
  float4 w4  = make_float4(wrow[16], wrow[17], wrow[18], wrow[19]);
  float4 w5  = make_float4(wrow[20], wrow[21], wrow[22], wrow[23]);
  float4 w6  = make_float4(wrow[24], wrow[25], wrow[26], wrow[27]);
  float4 w7  = make_float4(wrow[28], wrow[29], wrow[30], wrow[31]);
  float4 w8  = make_float4(wrow[32], wrow[33], wrow[34], wrow[35]);
  float4 w9  = make_float4(wrow[36], wrow[37], wrow[38], wrow[39]);
  float4 w10 = make_float4(wrow[40], wrow[41], wrow[42], wrow[43]);
  float4 w11 = make_float4(wrow[44], wrow[45], wrow[46], wrow[47]);
  float2 w12 = make_float2(wrow[48], wrow[49]);

  float c = c0[d * HID + jq];             // all 4 quad lanes hold the replica
  if (wr) hA[jq] = h0[d * HID + jq];
  __syncthreads();

  const int s = d ? -1 : 1;
  int t = d ? (T - 1) : 0;

  // depth-2 prefetch of this lane's pre element
  float c_pre = preD[(long long)t * G4 + col];
  int t1 = t + s; t1 = t1 < 0 ? 0 : (t1 > T - 1 ? T - 1 : t1);
  float n_pre = preD[(long long)t1 * G4 + col];

  for (int it = 0; it < T; it += 2) {
    LSTM_STEP(hA, hB)
    LSTM_STEP(hB, hA)
  }
}

// ---------------------------------------------------------------------------
// K3: feats[t][m] = bt[m] + Wt[m]·hs[t]   (dot over 100)
// ---------------------------------------------------------------------------
__global__ void k_feats(const float* __restrict__ hs, const float* __restrict__ Wt,
                        const float* __restrict__ bt, float* __restrict__ feats, int T) {
  int g = blockIdx.x * blockDim.x + threadIdx.x;
  if (g >= T * NTAG) return;
  int t = g / NTAG, m = g % NTAG;
  const float* h = hs + (long long)t * (2 * HID);
  const float* w = Wt + m * (2 * HID);
  float a = bt[m];
#pragma unroll
  for (int k = 0; k < 2 * HID; ++k) a += w[k] * h[k];
  feats[g] = a;
}

// ---------------------------------------------------------------------------
// K4a: serial Viterbi forward scan, 1 block x 64 threads (single wave).
// feats staged into LDS in two 40KB halves (cooperative float4 loads), so the
// serial chain reads LDS instead of L2/L3. Lane 0 stores fvh/terminal.
// ---------------------------------------------------------------------------
__global__ __launch_bounds__(64, 1) void k_vscan(const float* __restrict__ feats,
                        const float* __restrict__ trans,
                        float* __restrict__ fvh, float* __restrict__ misc,
                        float* __restrict__ out, int T) {
  __shared__ float sfeat[VCHUNK * NTAG];   // 40 KB
  const int tid = threadIdx.x;

  float tr[NTAG * NTAG];
#pragma unroll
  for (int i = 0; i < NTAG * NTAG; ++i) tr[i] = trans[i];

  float f0 = NEGV, f1 = NEGV, f2 = NEGV, f3 = 0.f, f4 = NEGV;

  for (int base = 0; base < T; base += VCHUNK) {
    const float4* src = (const float4*)(feats + (long long)base * NTAG);
    float4* dst = (float4*)sfeat;
    for (int i = tid; i < VCHUNK * NTAG / 4; i += 64) dst[i] = src[i];
    __syncthreads();

#pragma unroll 4
    for (int u = 0; u < VCHUNK; ++u) {
      int t = base + u;
      if (tid == 0) {
        fvh[t * 5 + 0] = f0; fvh[t * 5 + 1] = f1; fvh[t * 5 + 2] = f2;
        fvh[t * 5 + 3] = f3; fvh[t * 5 + 4] = f4;
      }
      float ft0 = sfeat[u * 5 + 0], ft1 = sfeat[u * 5 + 1], ft2 = sfeat[u * 5 + 2];
      float ft3 = sfeat[u * 5 + 3], ft4 = sfeat[u * 5 + 4];
      float n0 = fmaxf(fmaxf(fmaxf(f0 + tr[0],  f1 + tr[1]),  fmaxf(f2 + tr[2],  f3 + tr[3])),  f4 + tr[4])  + ft0;
      float n1 = fmaxf(fmaxf(fmaxf(f0 + tr[5],  f1 + tr[6]),  fmaxf(f2 + tr[7],  f3 + tr[8])),  f4 + tr[9])  + ft1;
      float n2 = fmaxf(fmaxf(fmaxf(f0 + tr[10], f1 + tr[11]), fmaxf(f2 + tr[12], f3 + tr[13])), f4 + tr[14]) + ft2;
      float n3 = fmaxf(fmaxf(fmaxf(f0 + tr[15], f1 + tr[16]), fmaxf(f2 + tr[17], f3 + tr[18])), f4 + tr[19]) + ft3;
      float n4 = fmaxf(fmaxf(fmaxf(f0 + tr[20], f1 + tr[21]), fmaxf(f2 + tr[22], f3 + tr[23])), f4 + tr[24]) + ft4;
      f0 = n0; f1 = n1; f2 = n2; f3 = n3; f4 = n4;
    }
    __syncthreads();
  }

  float b0 = f0 + tr[TAG_STOP * 5 + 0], b1 = f1 + tr[TAG_STOP * 5 + 1];
  float b2 = f2 + tr[TAG_STOP * 5 + 2], b3 = f3 + tr[TAG_STOP * 5 + 3];
  float b4 = f4 + tr[TAG_STOP * 5 + 4];
  int last = 0; float best = b0;
  if (b1 > best) { best = b1; last = 1; }
  if (b2 > best) { best = b2; last = 2; }
  if (b3 > best) { best = b3; last = 3; }
  if (b4 > best) { best = b4; last = 4; }
  if (tid == 0) { out[T] = best; misc[0] = (float)last; }
}

// ---------------------------------------------------------------------------
// K4b: parallel backpointer recompute + suffix-composition backtrace.
// ---------------------------------------------------------------------------
__global__ __launch_bounds__(1024) void k_vbt(const float* __restrict__ trans,
                        const float* __restrict__ fvh, const float* __restrict__ misc,
                        float* __restrict__ out, int T) {
  __shared__ unsigned int bufA[T_MAX];
  __shared__ unsigned int bufB[T_MAX];
  int tid = threadIdx.x;

  {
    float tr[NTAG * NTAG];
#pragma unroll
    for (int i = 0; i < NTAG * NTAG; ++i) tr[i] = trans[i];
    for (int t = tid; t < T; t += 1024) {
      unsigned pack;
      if (t == T - 1) {
        pack = 0u | (1u << 3) | (2u << 6) | (3u << 9) | (4u << 12);
      } else {
        const float* fv = fvh + (long long)(t + 1) * 5;
        float g0 = fv[0], g1 = fv[1], g2 = fv[2], g3 = fv[3], g4 = fv[4];
        pack = 0u;
#pragma unroll
        for (int nx = 0; nx < NTAG; ++nx) {
          float v0 = g0 + tr[nx * 5 + 0], v1 = g1 + tr[nx * 5 + 1], v2 = g2 + tr[nx * 5 + 2];
          float v3 = g3 + tr[nx * 5 + 3], v4 = g4 + tr[nx * 5 + 4];
          int bi = 0; float bv = v0;
          if (v1 > bv) { bv = v1; bi = 1; }
          if (v2 > bv) { bv = v2; bi = 2; }
          if (v3 > bv) { bv = v3; bi = 3; }
          if (v4 > bv) { bv = v4; bi = 4; }
          pack |= (unsigned)bi << (3 * nx);
        }
      }
      bufA[t] = pack;
    }
  }
  __syncthreads();

  unsigned int* cur = bufA;
  unsigned int* nxt = bufB;
  for (int dstep = 1; dstep < T; dstep <<= 1) {
    for (int t = tid; t < T; t += 1024) {
      unsigned v = cur[t];
      int u = t + dstep;
      if (u < T) {
        unsigned q = cur[u];
        unsigned r = 0u;
#pragma unroll
        for (int x = 0; x < NTAG; ++x) {
          unsigned qq = (q >> (3 * x)) & 7u;
          unsigned pp = (v >> (3 * qq)) & 7u;
          r |= pp << (3 * x);
        }
        v = r;
      }
      nxt[t] = v;
    }
    __syncthreads();
    unsigned int* tmp = cur; cur = nxt; nxt = tmp;
  }

  int last = (int)misc[0];
  for (int t = tid; t < T; t += 1024) {
    out[t] = (float)((cur[t] >> (3 * last)) & 7u);
  }
}

// ---------------------------------------------------------------------------
extern "C" void kernel_launch(void* const* d_in, const int* in_sizes, int n_in,
                              void* d_out, int out_size, void* d_ws, size_t ws_size,
                              hipStream_t stream) {
  const int*   sent  = (const int*)  d_in[0];
  const float* embed = (const float*)d_in[1];
  const float* Wih_f = (const float*)d_in[2];
  const float* Whh_f = (const float*)d_in[3];
  const float* b_f   = (const float*)d_in[4];
  const float* Wih_b = (const float*)d_in[5];
  const float* Whh_b = (const float*)d_in[6];
  const float* b_b   = (const float*)d_in[7];
  const float* Wt    = (const float*)d_in[8];
  const float* bt    = (const float*)d_in[9];
  const float* trans = (const float*)d_in[10];
  const float* h0    = (const float*)d_in[11];
  const float* c0    = (const float*)d_in[12];
  int T = in_sizes[0];

  float* out = (float*)d_out;
  float* pre   = (float*)d_ws;                       // 2*T*200 floats
  float* hs    = pre + 2 * (size_t)T * G4;           // T*100
  float* feats = hs + (size_t)T * 2 * HID;           // T*5
  float* fvh   = feats + (size_t)T * NTAG;           // (T+1)*5
  float* misc  = fvh + (size_t)(T + 1) * NTAG;       // 16

  k_embed_proj<<<T, 256, 0, stream>>>(sent, embed, Wih_f, b_f, Wih_b, b_b, pre, T);
  k_lstm<<<2, 256, 0, stream>>>(pre, Whh_f, Whh_b, h0, c0, hs, T);
  k_feats<<<(T * NTAG + 255) / 256, 256, 0, stream>>>(hs, Wt, bt, feats, T);
  k_vscan<<<1, 64, 0, stream>>>(feats, trans, fvh, misc, out, T);
  k_vbt<<<1, 1024, 0, stream>>>(trans, fvh, misc, out, T);
}